// Round 16
// baseline (11831.108 us; speedup 1.0000x reference)
//
#include <hip/hip_runtime.h>
#include <stdint.h>
#include <stddef.h>

#define B_ 16
#define T_ 4096
#define D_ 256
#define H_ 512
#define G3_ 1536

// ws layout
#define OFF_IG   ((size_t)0)                       // igates f16: 65536*1536*2 = 201326592
#define OFF_WT   ((size_t)201326592)               // W_ih^T packed float4: 256*1536*4 = 1572864
#define OFF_MB   ((size_t)202899456)               // mailboxes: 2*16*8*512*4 = 524288
#define WS_NEED  ((size_t)203423744)

#define PAR_STRIDE ((size_t)B_ * 8 * 512)           // words per parity buffer

typedef _Float16 h2_t __attribute__((ext_vector_type(2)));

#if defined(__has_builtin)
#if __has_builtin(__builtin_amdgcn_fdot2)
#define HAVE_FDOT2 1
#endif
#endif

__device__ __forceinline__ float fdot2f(uint32_t w, uint32_t h, float acc) {
  union { uint32_t u; h2_t v; } a, b;
  a.u = w; b.u = h;
#ifdef HAVE_FDOT2
  return __builtin_amdgcn_fdot2(a.v, b.v, acc, false);
#else
  return fmaf((float)a.v.x, (float)b.v.x, fmaf((float)a.v.y, (float)b.v.y, acc));
#endif
}

__device__ __forceinline__ uint32_t packh2(float a, float b) {
  union { h2_t v; uint32_t u; } x;
  x.v.x = (_Float16)a; x.v.y = (_Float16)b;
  return x.u;
}

__device__ __forceinline__ uint32_t f16bits(float a) {
  union { _Float16 h; uint16_t u; } x;
  x.h = (_Float16)a;
  return (uint32_t)x.u;
}

__device__ __forceinline__ float h2f(uint16_t u) {
  union { _Float16 h; uint16_t u; } x;
  x.u = u;
  return (float)x.h;
}

__device__ __forceinline__ float sigmoidf_(float x) {
  return 1.0f / (1.0f + __expf(-x));
}

__device__ __forceinline__ float tanhf_(float x) {
  x = fminf(fmaxf(x, -15.0f), 15.0f);
  float e = __expf(-2.0f * x);
  return (1.0f - e) / (1.0f + e);
}

// ---------------- Kernel 1: transpose+pack W_ih into [d/4][g] float4 ----------------
__global__ void __launch_bounds__(256) wt_kernel(const float* __restrict__ W, float4* __restrict__ Wt4) {
  int idx = blockIdx.x * 256 + threadIdx.x;   // over 1536*64
  if (idx >= G3_ * 64) return;
  int g = idx % G3_;
  int d4 = idx / G3_;
  float4 v = *(const float4*)(W + (size_t)g * D_ + 4 * d4);
  Wt4[(size_t)d4 * G3_ + g] = v;
}

// ---------------- Kernel 2: igates = xs @ W_ih^T + b  -> f16 ----------------
__global__ void __launch_bounds__(256) ig_kernel(const float* __restrict__ xs,
                                                 const float* __restrict__ Wt,
                                                 const float* __restrict__ bias,
                                                 _Float16* __restrict__ ig) {
  __shared__ float xls[16 * 256];
  const int m0 = blockIdx.x * 16;
  const int tid = threadIdx.x;

  const float4* xsrc = (const float4*)(xs + (size_t)m0 * D_);
  float4* xdst = (float4*)xls;
#pragma unroll
  for (int k = 0; k < 4; ++k) xdst[tid + 256 * k] = xsrc[tid + 256 * k];
  __syncthreads();

  float acc[6][16];
#pragma unroll
  for (int k = 0; k < 6; ++k)
#pragma unroll
    for (int m = 0; m < 16; ++m) acc[k][m] = 0.0f;

  const float4* Wt4 = (const float4*)Wt;
  const float4* lds4 = (const float4*)xls;

  for (int d4 = 0; d4 < 64; ++d4) {
    float4 w[6];
#pragma unroll
    for (int k = 0; k < 6; ++k) w[k] = Wt4[(size_t)d4 * G3_ + tid + 256 * k];
#pragma unroll
    for (int m = 0; m < 16; ++m) {
      float4 xv = lds4[m * 64 + d4];
#pragma unroll
      for (int k = 0; k < 6; ++k) {
        acc[k][m] = fmaf(w[k].x, xv.x, acc[k][m]);
        acc[k][m] = fmaf(w[k].y, xv.y, acc[k][m]);
        acc[k][m] = fmaf(w[k].z, xv.z, acc[k][m]);
        acc[k][m] = fmaf(w[k].w, xv.w, acc[k][m]);
      }
    }
  }

#pragma unroll
  for (int k = 0; k < 6; ++k) {
    float bb = bias[tid + 256 * k];
#pragma unroll
    for (int m = 0; m < 16; ++m) {
      ig[(size_t)(m0 + m) * G3_ + tid + 256 * k] = (_Float16)(acc[k][m] + bb);
    }
  }
}

// ---------------- Kernel 3: persistent recurrence, 2 batches per WG ----------------
// 64 WGs x 512 threads. WG wg: batch PAIR (b0 = wg>>3, b1 = b0+8), sub
// s = wg&7 owns columns [s*64, s*64+64) of both batches. Thread: q = tid&7,
// c = tid>>3, j = s*64+c. Weights (96 packed f16-pair VGPRs) are batch-
// independent -> shared by both batches.
// Per batch, protocol is R11's proven one (6700us): copy-major mailbox
// [parity][b][copy(8)][512], tagged words (tag<<16)|f16(h), producer lane q
// agent-stores column j into copy q; consumer WG-sub s polls copy s, thread
// tid -> word tid (1 poller/word); pipelined 2-deep dword sc1 poll.
// R16 SAFETY RULE (R14/R15 crashed): every poll block drains vmcnt(0)
// BEFORE exiting, with the load-target registers bound as OPERANDS of the
// drain asm itself -- deferring the drain lets the register allocator split/
// reuse the phys reg an in-flight load targets (variable keep-alive is NOT
// enough), producing wild stores. Self-contained polls are airtight.
// R16 LATENCY FIX: __syncthreads() compiler-drains vmcnt(0), so ig prefetch
// moved AFTER the barrier (R11 had it before -> ~900cy barrier stall/step);
// aged by dot+gates before the end-of-iteration drain -> free.
// INTERLEAVE: poll+stage A, poll+stage B, barrier, prefetch, compute+publish
// A, compute+publish B, vmcnt(0), rotate. A's store->MALL propagation
// overlaps B's poll+compute and vice versa.
// Race bound per batch unchanged from R11. Cross-replay: mailbox memset'd.
__global__ void __launch_bounds__(512, 1) rec_kernel(const _Float16* __restrict__ ig,
                                                     const float* __restrict__ Whh,
                                                     const float* __restrict__ bn,
                                                     uint32_t* __restrict__ mb,
                                                     float* __restrict__ out) {
  const int tid = threadIdx.x;
  const int wg = blockIdx.x;       // 0..63
  const int b0 = wg >> 3;          // 0..7
  const int b1 = b0 + 8;           // 8..15
  const int s = wg & 7;            // 0..7
  const int q = tid & 7;           // K-slice
  const int c = tid >> 3;          // 0..63
  const int j = s * 64 + c;        // 0..511

  // ---- load + pack weights into registers (96 dwords, shared by batches) ----
  uint32_t wr[32], wz[32], wn[32];
  {
    const float4* s0 = (const float4*)(Whh + (size_t)j * H_ + q * 64);
    const float4* s1 = (const float4*)(Whh + (size_t)(j + H_) * H_ + q * 64);
    const float4* s2 = (const float4*)(Whh + (size_t)(j + 2 * H_) * H_ + q * 64);
#pragma unroll
    for (int i = 0; i < 16; ++i) {
      float4 v0 = s0[i]; wr[2 * i] = packh2(v0.x, v0.y); wr[2 * i + 1] = packh2(v0.z, v0.w);
      float4 v1 = s1[i]; wz[2 * i] = packh2(v1.x, v1.y); wz[2 * i + 1] = packh2(v1.z, v1.w);
      float4 v2 = s2[i]; wn[2 * i] = packh2(v2.x, v2.y); wn[2 * i + 1] = packh2(v2.z, v2.w);
    }
  }
  const float bnj = bn[j];

  // LDS h-pairs: [batch][parity][8 regions][32 u32 + 4 pad]
  __shared__ uint32_t hl[2][2][8][36];
  uint16_t* hl16 = (uint16_t*)hl;   // per-batch stride 1152 u16, per-parity 576

  // mailbox addresses (copy-major, R11 layout)
  uint32_t* poll0 = mb + ((size_t)b0 * 8 + s) * 512 + tid;
  uint32_t* poll1 = mb + ((size_t)b1 * 8 + s) * 512 + tid;
  uint32_t* pub0  = mb + ((size_t)b0 * 8 + q) * 512 + j;
  uint32_t* pub1  = mb + ((size_t)b1 * 8 + q) * 512 + j;

  const uint16_t* ig16 = (const uint16_t*)ig;
  size_t igb0 = (size_t)b0 * T_ * G3_;
  size_t igb1 = (size_t)b1 * T_ * G3_;

  // ig pipelines, 3-deep, per batch
  uint16_t cr0 = ig16[igb0 + j], cz0 = ig16[igb0 + j + H_], cn0 = ig16[igb0 + j + 2 * H_];
  uint16_t r10 = ig16[igb0 + G3_ + j], z10 = ig16[igb0 + G3_ + j + H_], n10 = ig16[igb0 + G3_ + j + 2 * H_];
  uint16_t r20 = ig16[igb0 + 2 * (size_t)G3_ + j], z20 = ig16[igb0 + 2 * (size_t)G3_ + j + H_], n20 = ig16[igb0 + 2 * (size_t)G3_ + j + 2 * H_];
  uint16_t cr1 = ig16[igb1 + j], cz1 = ig16[igb1 + j + H_], cn1 = ig16[igb1 + j + 2 * H_];
  uint16_t r11_ = ig16[igb1 + G3_ + j], z11 = ig16[igb1 + G3_ + j + H_], n11 = ig16[igb1 + G3_ + j + 2 * H_];
  uint16_t r21 = ig16[igb1 + 2 * (size_t)G3_ + j], z21 = ig16[igb1 + 2 * (size_t)G3_ + j + H_], n21 = ig16[igb1 + 2 * (size_t)G3_ + j + 2 * H_];

  float hprev0 = 0.0f, hprev1 = 0.0f;

  for (int t = 0; t < T_; ++t) {
    uint16_t fr0 = 0, fz0 = 0, fn0 = 0, fr1 = 0, fz1 = 0, fn1 = 0;

    if (t > 0) {
      const uint32_t want = (uint32_t)t;
      const size_t poff = (size_t)(t & 1) * PAR_STRIDE;

      // ---- poll batch A (self-contained: drains before exit) ----
      {
        uint32_t* pb = poll0 + poff;
        uint32_t va, vb, a0;
        asm volatile("global_load_dword %0, %2, off sc1\n\t"
                     "global_load_dword %1, %2, off sc1"
                     : "=&v"(va), "=&v"(vb) : "v"(pb) : "memory");
        int it = 0;
        for (;;) {
          asm volatile("s_waitcnt vmcnt(1)" ::: "memory");
          __builtin_amdgcn_sched_barrier(0);
          a0 = va;
          if ((a0 >> 16) == want) break;
          asm volatile("global_load_dword %0, %1, off sc1" : "=&v"(va) : "v"(pb) : "memory");
          asm volatile("s_waitcnt vmcnt(1)" ::: "memory");
          __builtin_amdgcn_sched_barrier(0);
          a0 = vb;
          if ((a0 >> 16) == want) break;
          asm volatile("global_load_dword %0, %1, off sc1" : "=&v"(vb) : "v"(pb) : "memory");
          if (++it > (1 << 20)) { a0 = 0x7C00u; break; }   // visible poison, no hang
        }
        // drain leftover; va/vb are OPERANDS so their phys regs stay
        // allocated until the in-flight loads complete (R16 safety rule)
        asm volatile("s_waitcnt vmcnt(0)" :: "v"(va), "v"(vb) : "memory");
        __builtin_amdgcn_sched_barrier(0);
        hl16[(t & 1) * 576 + (tid >> 6) * 72 + (tid & 63)] = (uint16_t)(a0 & 0xFFFFu);
      }

      // ---- poll batch B (identical, counter is clean on entry) ----
      {
        uint32_t* pb = poll1 + poff;
        uint32_t va, vb, a1;
        asm volatile("global_load_dword %0, %2, off sc1\n\t"
                     "global_load_dword %1, %2, off sc1"
                     : "=&v"(va), "=&v"(vb) : "v"(pb) : "memory");
        int it = 0;
        for (;;) {
          asm volatile("s_waitcnt vmcnt(1)" ::: "memory");
          __builtin_amdgcn_sched_barrier(0);
          a1 = va;
          if ((a1 >> 16) == want) break;
          asm volatile("global_load_dword %0, %1, off sc1" : "=&v"(va) : "v"(pb) : "memory");
          asm volatile("s_waitcnt vmcnt(1)" ::: "memory");
          __builtin_amdgcn_sched_barrier(0);
          a1 = vb;
          if ((a1 >> 16) == want) break;
          asm volatile("global_load_dword %0, %1, off sc1" : "=&v"(vb) : "v"(pb) : "memory");
          if (++it > (1 << 20)) { a1 = 0x7C00u; break; }
        }
        asm volatile("s_waitcnt vmcnt(0)" :: "v"(va), "v"(vb) : "memory");
        __builtin_amdgcn_sched_barrier(0);
        hl16[1152 + (t & 1) * 576 + (tid >> 6) * 72 + (tid & 63)] = (uint16_t)(a1 & 0xFFFFu);
      }
    }

    __syncthreads();   // single barrier per iteration; VMEM counter is clean
                       // here (polls drained) so the compiler's pre-barrier
                       // vmcnt(0) is free (R16 latency fix)

    // t+3 ig prefetch AFTER the barrier: aged by dot+gates before the
    // end-of-iteration drain -> never stalls a barrier or a poll
    if (t + 3 < T_) {
      const size_t fb0 = igb0 + 3 * (size_t)G3_;
      const size_t fb1 = igb1 + 3 * (size_t)G3_;
      fr0 = ig16[fb0 + j]; fz0 = ig16[fb0 + j + H_]; fn0 = ig16[fb0 + j + 2 * H_];
      fr1 = ig16[fb1 + j]; fz1 = ig16[fb1 + j + H_]; fn1 = ig16[fb1 + j + 2 * H_];
    }

    // ================= batch A: dot, gates, publish =================
    {
      float ar = 0.0f, az = 0.0f, an = 0.0f;
      if (t > 0) {
        const uint4* hq = (const uint4*)hl[0][t & 1][q];
        uint4 hv[8];
#pragma unroll
        for (int i = 0; i < 8; ++i) hv[i] = hq[i];
        float ar0 = 0.0f, az0 = 0.0f, an0 = 0.0f, ar1 = 0.0f, az1 = 0.0f, an1 = 0.0f;
#pragma unroll
        for (int i = 0; i < 4; ++i) {
          ar0 = fdot2f(wr[4 * i + 0], hv[i].x, ar0); az0 = fdot2f(wz[4 * i + 0], hv[i].x, az0); an0 = fdot2f(wn[4 * i + 0], hv[i].x, an0);
          ar0 = fdot2f(wr[4 * i + 1], hv[i].y, ar0); az0 = fdot2f(wz[4 * i + 1], hv[i].y, az0); an0 = fdot2f(wn[4 * i + 1], hv[i].y, an0);
          ar0 = fdot2f(wr[4 * i + 2], hv[i].z, ar0); az0 = fdot2f(wz[4 * i + 2], hv[i].z, az0); an0 = fdot2f(wn[4 * i + 2], hv[i].z, an0);
          ar0 = fdot2f(wr[4 * i + 3], hv[i].w, ar0); az0 = fdot2f(wz[4 * i + 3], hv[i].w, az0); an0 = fdot2f(wn[4 * i + 3], hv[i].w, an0);
        }
#pragma unroll
        for (int i = 4; i < 8; ++i) {
          ar1 = fdot2f(wr[4 * i + 0], hv[i].x, ar1); az1 = fdot2f(wz[4 * i + 0], hv[i].x, az1); an1 = fdot2f(wn[4 * i + 0], hv[i].x, an1);
          ar1 = fdot2f(wr[4 * i + 1], hv[i].y, ar1); az1 = fdot2f(wz[4 * i + 1], hv[i].y, az1); an1 = fdot2f(wn[4 * i + 1], hv[i].y, an1);
          ar1 = fdot2f(wr[4 * i + 2], hv[i].z, ar1); az1 = fdot2f(wz[4 * i + 2], hv[i].z, az1); an1 = fdot2f(wn[4 * i + 2], hv[i].z, an1);
          ar1 = fdot2f(wr[4 * i + 3], hv[i].w, ar1); az1 = fdot2f(wz[4 * i + 3], hv[i].w, az1); an1 = fdot2f(wn[4 * i + 3], hv[i].w, an1);
        }
        ar = ar0 + ar1; az = az0 + az1; an = an0 + an1;
        ar += __shfl_xor(ar, 1); ar += __shfl_xor(ar, 2); ar += __shfl_xor(ar, 4);
        az += __shfl_xor(az, 1); az += __shfl_xor(az, 2); az += __shfl_xor(az, 4);
        an += __shfl_xor(an, 1); an += __shfl_xor(an, 2); an += __shfl_xor(an, 4);
      }
      const float igr = h2f(cr0), igz = h2f(cz0), ign = h2f(cn0);
      const float r = sigmoidf_(igr + ar);
      const float z = sigmoidf_(igz + az);
      const float n = tanhf_(ign + r * (an + bnj));
      const float hnew = n + z * (hprev0 - n);
      hprev0 = hnew;
      const uint32_t wv = ((uint32_t)(t + 1) << 16) | f16bits(hnew);
      __hip_atomic_store(pub0 + (size_t)((t + 1) & 1) * PAR_STRIDE, wv,
                         __ATOMIC_RELAXED, __HIP_MEMORY_SCOPE_AGENT);
      if (q == 0) out[((size_t)b0 * T_ + t) * H_ + j] = hnew;
    }

    // ================= batch B: dot, gates, publish =================
    {
      float ar = 0.0f, az = 0.0f, an = 0.0f;
      if (t > 0) {
        const uint4* hq = (const uint4*)hl[1][t & 1][q];
        uint4 hv[8];
#pragma unroll
        for (int i = 0; i < 8; ++i) hv[i] = hq[i];
        float ar0 = 0.0f, az0 = 0.0f, an0 = 0.0f, ar1 = 0.0f, az1 = 0.0f, an1 = 0.0f;
#pragma unroll
        for (int i = 0; i < 4; ++i) {
          ar0 = fdot2f(wr[4 * i + 0], hv[i].x, ar0); az0 = fdot2f(wz[4 * i + 0], hv[i].x, az0); an0 = fdot2f(wn[4 * i + 0], hv[i].x, an0);
          ar0 = fdot2f(wr[4 * i + 1], hv[i].y, ar0); az0 = fdot2f(wz[4 * i + 1], hv[i].y, az0); an0 = fdot2f(wn[4 * i + 1], hv[i].y, an0);
          ar0 = fdot2f(wr[4 * i + 2], hv[i].z, ar0); az0 = fdot2f(wz[4 * i + 2], hv[i].z, az0); an0 = fdot2f(wn[4 * i + 2], hv[i].z, an0);
          ar0 = fdot2f(wr[4 * i + 3], hv[i].w, ar0); az0 = fdot2f(wz[4 * i + 3], hv[i].w, az0); an0 = fdot2f(wn[4 * i + 3], hv[i].w, an0);
        }
#pragma unroll
        for (int i = 4; i < 8; ++i) {
          ar1 = fdot2f(wr[4 * i + 0], hv[i].x, ar1); az1 = fdot2f(wz[4 * i + 0], hv[i].x, az1); an1 = fdot2f(wn[4 * i + 0], hv[i].x, an1);
          ar1 = fdot2f(wr[4 * i + 1], hv[i].y, ar1); az1 = fdot2f(wz[4 * i + 1], hv[i].y, az1); an1 = fdot2f(wn[4 * i + 1], hv[i].y, an1);
          ar1 = fdot2f(wr[4 * i + 2], hv[i].z, ar1); az1 = fdot2f(wz[4 * i + 2], hv[i].z, az1); an1 = fdot2f(wn[4 * i + 2], hv[i].z, an1);
          ar1 = fdot2f(wr[4 * i + 3], hv[i].w, ar1); az1 = fdot2f(wz[4 * i + 3], hv[i].w, az1); an1 = fdot2f(wn[4 * i + 3], hv[i].w, an1);
        }
        ar = ar0 + ar1; az = az0 + az1; an = an0 + an1;
        ar += __shfl_xor(ar, 1); ar += __shfl_xor(ar, 2); ar += __shfl_xor(ar, 4);
        az += __shfl_xor(az, 1); az += __shfl_xor(az, 2); az += __shfl_xor(az, 4);
        an += __shfl_xor(an, 1); an += __shfl_xor(an, 2); an += __shfl_xor(an, 4);
      }
      const float igr = h2f(cr1), igz = h2f(cz1), ign = h2f(cn1);
      const float r = sigmoidf_(igr + ar);
      const float z = sigmoidf_(igz + az);
      const float n = tanhf_(ign + r * (an + bnj));
      const float hnew = n + z * (hprev1 - n);
      hprev1 = hnew;
      const uint32_t wv = ((uint32_t)(t + 1) << 16) | f16bits(hnew);
      __hip_atomic_store(pub1 + (size_t)((t + 1) & 1) * PAR_STRIDE, wv,
                         __ATOMIC_RELAXED, __HIP_MEMORY_SCOPE_AGENT);
      if (q == 0) out[((size_t)b1 * T_ + t) * H_ + j] = hnew;
    }

    // drain stores + aged prefetches (overlaps MALL propagation consumers
    // wait for anyway); only compiler-tracked VMEM is outstanding here
    asm volatile("s_waitcnt vmcnt(0)" ::: "memory");
    __builtin_amdgcn_sched_barrier(0);

    // rotate ig pipelines
    cr0 = r10; cz0 = z10; cn0 = n10;  r10 = r20; z10 = z20; n10 = n20;  r20 = fr0; z20 = fz0; n20 = fn0;
    cr1 = r11_; cz1 = z11; cn1 = n11; r11_ = r21; z11 = z21; n11 = n21; r21 = fr1; z21 = fz1; n21 = fn1;
    igb0 += G3_;
    igb1 += G3_;
  }
}

// ---------------- Fallback: naive (only if ws too small) ----------------
__global__ void __launch_bounds__(512) naive_kernel(const float* __restrict__ xs,
                                                    const float* __restrict__ Wih,
                                                    const float* __restrict__ Whh,
                                                    const float* __restrict__ bias,
                                                    const float* __restrict__ bn,
                                                    float* __restrict__ out) {
  const int b = blockIdx.x;
  const int j = threadIdx.x;
  __shared__ float h[H_];
  __shared__ float xr[D_];
  h[j] = 0.0f;
  __syncthreads();
  for (int t = 0; t < T_; ++t) {
    if (j < D_) xr[j] = xs[((size_t)b * T_ + t) * D_ + j];
    __syncthreads();
    float a[2];
#pragma unroll
    for (int g = 0; g < 2; ++g) {
      const int row = j + g * H_;
      float ssum = bias[row];
      const float* wi = Wih + (size_t)row * D_;
      for (int d = 0; d < D_; ++d) ssum = fmaf(wi[d], xr[d], ssum);
      const float* wh = Whh + (size_t)row * H_;
      for (int kk = 0; kk < H_; ++kk) ssum = fmaf(wh[kk], h[kk], ssum);
      a[g] = ssum;
    }
    const float r = sigmoidf_(a[0]);
    const float z = sigmoidf_(a[1]);
    float i_n = bias[j + 2 * H_];
    {
      const float* wi = Wih + (size_t)(j + 2 * H_) * D_;
      for (int d = 0; d < D_; ++d) i_n = fmaf(wi[d], xr[d], i_n);
    }
    float h_n = 0.0f;
    {
      const float* wh = Whh + (size_t)(j + 2 * H_) * H_;
      for (int kk = 0; kk < H_; ++kk) h_n = fmaf(wh[kk], h[kk], h_n);
    }
    const float nn = tanhf_(i_n + r * (h_n + bn[j]));
    const float hnew = nn + z * (h[j] - nn);
    __syncthreads();
    h[j] = hnew;
    out[((size_t)b * T_ + t) * H_ + j] = hnew;
  }
}

extern "C" void kernel_launch(void* const* d_in, const int* in_sizes, int n_in,
                              void* d_out, int out_size, void* d_ws, size_t ws_size,
                              hipStream_t stream) {
  const float* xs  = (const float*)d_in[0];
  const float* Wih = (const float*)d_in[1];
  const float* Whh = (const float*)d_in[2];
  const float* bia = (const float*)d_in[3];
  const float* bnp = (const float*)d_in[4];
  float* out = (float*)d_out;

  if (ws_size >= WS_NEED) {
    char* ws = (char*)d_ws;
    _Float16* igp = (_Float16*)(ws + OFF_IG);
    float* wtp = (float*)(ws + OFF_WT);
    uint32_t* mbp = (uint32_t*)(ws + OFF_MB);

    // zero tag mailboxes (stale-tag kill across graph replays)
    (void)hipMemsetAsync(mbp, 0, 2 * PAR_STRIDE * sizeof(uint32_t), stream);

    wt_kernel<<<dim3(384), dim3(256), 0, stream>>>(Wih, (float4*)wtp);
    ig_kernel<<<dim3((B_ * T_) / 16), dim3(256), 0, stream>>>(xs, wtp, bia, igp);
    rec_kernel<<<dim3(64), dim3(512), 0, stream>>>(igp, Whh, bnp, mbp, out);
  } else {
    naive_kernel<<<dim3(B_), dim3(H_), 0, stream>>>(xs, Wih, Whh, bia, bnp, out);
  }
}

// Round 17
// 7288.122 us; speedup vs baseline: 1.6233x; 1.6233x over previous
//
#include <hip/hip_runtime.h>
#include <stdint.h>
#include <stddef.h>

#define B_ 16
#define T_ 4096
#define D_ 256
#define H_ 512
#define G3_ 1536

// ws layout
#define OFF_IG   ((size_t)0)                       // igates f16: 65536*1536*2 = 201326592
#define OFF_WT   ((size_t)201326592)               // W_ih^T packed float4: 256*1536*4 = 1572864
#define OFF_MB   ((size_t)202899456)               // mailboxes: 2*16*8*512*4 = 524288
#define WS_NEED  ((size_t)203423744)

#define PAR_STRIDE ((size_t)B_ * 8 * 512)           // words per parity buffer

typedef _Float16 h2_t __attribute__((ext_vector_type(2)));

#if defined(__has_builtin)
#if __has_builtin(__builtin_amdgcn_fdot2)
#define HAVE_FDOT2 1
#endif
#endif

__device__ __forceinline__ float fdot2f(uint32_t w, uint32_t h, float acc) {
  union { uint32_t u; h2_t v; } a, b;
  a.u = w; b.u = h;
#ifdef HAVE_FDOT2
  return __builtin_amdgcn_fdot2(a.v, b.v, acc, false);
#else
  return fmaf((float)a.v.x, (float)b.v.x, fmaf((float)a.v.y, (float)b.v.y, acc));
#endif
}

__device__ __forceinline__ uint32_t packh2(float a, float b) {
  union { h2_t v; uint32_t u; } x;
  x.v.x = (_Float16)a; x.v.y = (_Float16)b;
  return x.u;
}

__device__ __forceinline__ uint32_t f16bits(float a) {
  union { _Float16 h; uint16_t u; } x;
  x.h = (_Float16)a;
  return (uint32_t)x.u;
}

__device__ __forceinline__ float h2f(uint16_t u) {
  union { _Float16 h; uint16_t u; } x;
  x.u = u;
  return (float)x.h;
}

__device__ __forceinline__ float sigmoidf_(float x) {
  return 1.0f / (1.0f + __expf(-x));
}

__device__ __forceinline__ float tanhf_(float x) {
  x = fminf(fmaxf(x, -15.0f), 15.0f);
  float e = __expf(-2.0f * x);
  return (1.0f - e) / (1.0f + e);
}

// ---------------- Kernel 1: transpose+pack W_ih into [d/4][g] float4 ----------------
__global__ void __launch_bounds__(256) wt_kernel(const float* __restrict__ W, float4* __restrict__ Wt4) {
  int idx = blockIdx.x * 256 + threadIdx.x;   // over 1536*64
  if (idx >= G3_ * 64) return;
  int g = idx % G3_;
  int d4 = idx / G3_;
  float4 v = *(const float4*)(W + (size_t)g * D_ + 4 * d4);
  Wt4[(size_t)d4 * G3_ + g] = v;
}

// ---------------- Kernel 2: igates = xs @ W_ih^T + b  -> f16 ----------------
__global__ void __launch_bounds__(256) ig_kernel(const float* __restrict__ xs,
                                                 const float* __restrict__ Wt,
                                                 const float* __restrict__ bias,
                                                 _Float16* __restrict__ ig) {
  __shared__ float xls[16 * 256];
  const int m0 = blockIdx.x * 16;
  const int tid = threadIdx.x;

  const float4* xsrc = (const float4*)(xs + (size_t)m0 * D_);
  float4* xdst = (float4*)xls;
#pragma unroll
  for (int k = 0; k < 4; ++k) xdst[tid + 256 * k] = xsrc[tid + 256 * k];
  __syncthreads();

  float acc[6][16];
#pragma unroll
  for (int k = 0; k < 6; ++k)
#pragma unroll
    for (int m = 0; m < 16; ++m) acc[k][m] = 0.0f;

  const float4* Wt4 = (const float4*)Wt;
  const float4* lds4 = (const float4*)xls;

  for (int d4 = 0; d4 < 64; ++d4) {
    float4 w[6];
#pragma unroll
    for (int k = 0; k < 6; ++k) w[k] = Wt4[(size_t)d4 * G3_ + tid + 256 * k];
#pragma unroll
    for (int m = 0; m < 16; ++m) {
      float4 xv = lds4[m * 64 + d4];
#pragma unroll
      for (int k = 0; k < 6; ++k) {
        acc[k][m] = fmaf(w[k].x, xv.x, acc[k][m]);
        acc[k][m] = fmaf(w[k].y, xv.y, acc[k][m]);
        acc[k][m] = fmaf(w[k].z, xv.z, acc[k][m]);
        acc[k][m] = fmaf(w[k].w, xv.w, acc[k][m]);
      }
    }
  }

#pragma unroll
  for (int k = 0; k < 6; ++k) {
    float bb = bias[tid + 256 * k];
#pragma unroll
    for (int m = 0; m < 16; ++m) {
      ig[(size_t)(m0 + m) * G3_ + tid + 256 * k] = (_Float16)(acc[k][m] + bb);
    }
  }
}

// ---------------- Kernel 3: persistent recurrence (R11 topology + fixes) ----------------
// 128 WGs x 512 threads. WG wg: batch b = wg>>3, sub s = wg&7 owns columns
// [s*64, s*64+64). Thread: q = tid&7 (K-slice of 64), c = tid>>3 (0..63),
// j = s*64 + c. Weights: rows {j, j+512, j+1024} x K[q*64,+64) = 96 packed
// f16-pair VGPRs.
// Exchange (R11-proven, best=6700us): copy-major mailbox
// [parity][b][copy(8)][512], tagged words (tag<<16)|f16(h), agent/MALL
// scope. Producer: lane q agent-stores column j into copy q. Consumer: WG s
// polls copy s, thread tid -> word tid (1 poller/word); pipelined 2-deep
// dword sc1 poll, vmcnt(1) alternating.
// R16 SAFETY RULE: the poll block drains vmcnt(0) BEFORE exiting, with the
// load-target registers bound as OPERANDS of the drain asm (deferred drains
// let regalloc split/reuse the target phys reg of an in-flight load -> wild
// store; R14/R15 crashes).
// R17 LATENCY FIX: ig prefetch issued AFTER the barrier (R11 issued it just
// before __syncthreads, whose compiler-emitted vmcnt(0) stalled ~900cy on
// the fresh HBM loads every step). Post-barrier, the prefetches age under
// dot+gates+publish before the end-of-iteration drain -> ~free.
// Race bound (R11): overwrite(tag t+2, parity t&1) <- producer detect(t+1)
// <- all WGs publish(t+1) <- their barrier(t) <- all lanes' reads of
// slot(t). Cross-replay: mailbox memset'd in-stream each launch.
__global__ void __launch_bounds__(512, 1) rec_kernel(const _Float16* __restrict__ ig,
                                                     const float* __restrict__ Whh,
                                                     const float* __restrict__ bn,
                                                     uint32_t* __restrict__ mb,
                                                     float* __restrict__ out) {
  const int tid = threadIdx.x;
  const int wg = blockIdx.x;       // 0..127
  const int b = wg >> 3;           // 0..15
  const int s = wg & 7;            // 0..7
  const int q = tid & 7;           // K-slice
  const int c = tid >> 3;          // 0..63
  const int j = s * 64 + c;        // 0..511

  // ---- load + pack weights into registers (96 dwords) ----
  uint32_t wr[32], wz[32], wn[32];
  {
    const float4* s0 = (const float4*)(Whh + (size_t)j * H_ + q * 64);
    const float4* s1 = (const float4*)(Whh + (size_t)(j + H_) * H_ + q * 64);
    const float4* s2 = (const float4*)(Whh + (size_t)(j + 2 * H_) * H_ + q * 64);
#pragma unroll
    for (int i = 0; i < 16; ++i) {
      float4 v0 = s0[i]; wr[2 * i] = packh2(v0.x, v0.y); wr[2 * i + 1] = packh2(v0.z, v0.w);
      float4 v1 = s1[i]; wz[2 * i] = packh2(v1.x, v1.y); wz[2 * i + 1] = packh2(v1.z, v1.w);
      float4 v2 = s2[i]; wn[2 * i] = packh2(v2.x, v2.y); wn[2 * i + 1] = packh2(v2.z, v2.w);
    }
  }
  const float bnj = bn[j];

  // double-buffered padded LDS h-pairs: [parity][8 regions][32 u32 + 4 pad]
  __shared__ uint32_t hl[2][8][36];
  uint16_t* hl16 = (uint16_t*)hl;

  // mailbox addresses (copy-major, R11 layout)
  uint32_t* mypoll = mb + ((size_t)b * 8 + s) * 512 + tid;   // copy s, word tid
  uint32_t* mypub  = mb + ((size_t)b * 8 + q) * 512 + j;     // copy q, word j

  const uint16_t* ig16 = (const uint16_t*)ig;
  size_t igbase = (size_t)b * T_ * G3_;

  // ig pipeline, 3-deep: cur(t), n1(t+1), n2(t+2); t+3 issued post-barrier
  uint16_t cr = ig16[igbase + j];
  uint16_t cz = ig16[igbase + j + H_];
  uint16_t cn = ig16[igbase + j + 2 * H_];
  uint16_t r1 = ig16[igbase + G3_ + j];
  uint16_t z1 = ig16[igbase + G3_ + j + H_];
  uint16_t n1 = ig16[igbase + G3_ + j + 2 * H_];
  uint16_t r2 = ig16[igbase + 2 * (size_t)G3_ + j];
  uint16_t z2 = ig16[igbase + 2 * (size_t)G3_ + j + H_];
  uint16_t n2 = ig16[igbase + 2 * (size_t)G3_ + j + 2 * H_];

  float hprev = 0.0f;

  for (int t = 0; t < T_; ++t) {
    uint16_t fr = 0, fz = 0, fn = 0;

    if (t > 0) {
      // ---- pipelined 2-deep poll of my single word (self-contained) ----
      uint32_t* pb = mypoll + (size_t)(t & 1) * PAR_STRIDE;
      const uint32_t want = (uint32_t)t;
      uint32_t va, vb, a0;
      asm volatile("global_load_dword %0, %2, off sc1\n\t"
                   "global_load_dword %1, %2, off sc1"
                   : "=&v"(va), "=&v"(vb) : "v"(pb) : "memory");
      int it = 0;
      for (;;) {
        asm volatile("s_waitcnt vmcnt(1)" ::: "memory");
        __builtin_amdgcn_sched_barrier(0);
        a0 = va;
        if ((a0 >> 16) == want) break;
        asm volatile("global_load_dword %0, %1, off sc1" : "=&v"(va) : "v"(pb) : "memory");
        asm volatile("s_waitcnt vmcnt(1)" ::: "memory");
        __builtin_amdgcn_sched_barrier(0);
        a0 = vb;
        if ((a0 >> 16) == want) break;
        asm volatile("global_load_dword %0, %1, off sc1" : "=&v"(vb) : "v"(pb) : "memory");
        if (++it > (1 << 20)) { a0 = 0x7C00u; break; }   // visible poison, no hang
      }
      // drain leftover; va/vb bound as OPERANDS (R16 safety rule)
      asm volatile("s_waitcnt vmcnt(0)" :: "v"(va), "v"(vb) : "memory");
      __builtin_amdgcn_sched_barrier(0);

      // stage my h column into LDS: word tid -> region tid>>6, offset tid&63
      hl16[(t & 1) * 576 + (tid >> 6) * 72 + (tid & 63)] = (uint16_t)(a0 & 0xFFFFu);
    }

    __syncthreads();   // single barrier per step; VMEM counter is clean here
                       // (poll drained) so the compiler's pre-barrier
                       // vmcnt(0) is free (R17 fix)

    // t+3 ig prefetch AFTER the barrier: ages under dot+gates+publish
    // before the end-of-iteration drain -> never stalls barrier or poll
    if (t + 3 < T_) {
      const size_t fb = igbase + 3 * (size_t)G3_;
      fr = ig16[fb + j];
      fz = ig16[fb + j + H_];
      fn = ig16[fb + j + 2 * H_];
    }

    float ar = 0.0f, az = 0.0f, an = 0.0f;
    if (t > 0) {
      // ---- dot: 3 gates x 32 fdot2, 2 chains per gate; conflict-free b128 ----
      const uint4* hq = (const uint4*)hl[t & 1][q];
      uint4 hv[8];
#pragma unroll
      for (int i = 0; i < 8; ++i) hv[i] = hq[i];
      float ar0 = 0.0f, az0 = 0.0f, an0 = 0.0f;
      float ar1 = 0.0f, az1 = 0.0f, an1 = 0.0f;
#pragma unroll
      for (int i = 0; i < 4; ++i) {
        ar0 = fdot2f(wr[4 * i + 0], hv[i].x, ar0); az0 = fdot2f(wz[4 * i + 0], hv[i].x, az0); an0 = fdot2f(wn[4 * i + 0], hv[i].x, an0);
        ar0 = fdot2f(wr[4 * i + 1], hv[i].y, ar0); az0 = fdot2f(wz[4 * i + 1], hv[i].y, az0); an0 = fdot2f(wn[4 * i + 1], hv[i].y, an0);
        ar0 = fdot2f(wr[4 * i + 2], hv[i].z, ar0); az0 = fdot2f(wz[4 * i + 2], hv[i].z, az0); an0 = fdot2f(wn[4 * i + 2], hv[i].z, an0);
        ar0 = fdot2f(wr[4 * i + 3], hv[i].w, ar0); az0 = fdot2f(wz[4 * i + 3], hv[i].w, az0); an0 = fdot2f(wn[4 * i + 3], hv[i].w, an0);
      }
#pragma unroll
      for (int i = 4; i < 8; ++i) {
        ar1 = fdot2f(wr[4 * i + 0], hv[i].x, ar1); az1 = fdot2f(wz[4 * i + 0], hv[i].x, az1); an1 = fdot2f(wn[4 * i + 0], hv[i].x, an1);
        ar1 = fdot2f(wr[4 * i + 1], hv[i].y, ar1); az1 = fdot2f(wz[4 * i + 1], hv[i].y, az1); an1 = fdot2f(wn[4 * i + 1], hv[i].y, an1);
        ar1 = fdot2f(wr[4 * i + 2], hv[i].z, ar1); az1 = fdot2f(wz[4 * i + 2], hv[i].z, az1); an1 = fdot2f(wn[4 * i + 2], hv[i].z, an1);
        ar1 = fdot2f(wr[4 * i + 3], hv[i].w, ar1); az1 = fdot2f(wz[4 * i + 3], hv[i].w, az1); an1 = fdot2f(wn[4 * i + 3], hv[i].w, an1);
      }
      ar = ar0 + ar1; az = az0 + az1; an = an0 + an1;
      // reduce across the 8 K-slice lanes (lanes 8c..8c+7)
      ar += __shfl_xor(ar, 1); ar += __shfl_xor(ar, 2); ar += __shfl_xor(ar, 4);
      az += __shfl_xor(az, 1); az += __shfl_xor(az, 2); az += __shfl_xor(az, 4);
      an += __shfl_xor(an, 1); an += __shfl_xor(an, 2); an += __shfl_xor(an, 4);
    }

    // ---- gates (redundant on all 8 q-lanes of a column) ----
    const float igr = h2f(cr), igz = h2f(cz), ign = h2f(cn);
    const float r = sigmoidf_(igr + ar);
    const float z = sigmoidf_(igz + az);
    const float n = tanhf_(ign + r * (an + bnj));
    const float hnew = n + z * (hprev - n);
    hprev = hnew;

    // ---- publish: 1 tagged agent store per thread (lane q -> copy q) ----
    const uint32_t wv = ((uint32_t)(t + 1) << 16) | f16bits(hnew);
    __hip_atomic_store(mypub + (size_t)((t + 1) & 1) * PAR_STRIDE, wv,
                       __ATOMIC_RELAXED, __HIP_MEMORY_SCOPE_AGENT);
    if (q == 0) {
      out[((size_t)b * T_ + t) * H_ + j] = hnew;
    }
    // drain stores + aged prefetches (overlaps MALL propagation consumers
    // wait for anyway); keeps next poll's vmcnt counting only its own loads
    asm volatile("s_waitcnt vmcnt(0)" ::: "memory");
    __builtin_amdgcn_sched_barrier(0);

    // rotate ig pipeline
    cr = r1; cz = z1; cn = n1;
    r1 = r2; z1 = z2; n1 = n2;
    r2 = fr; z2 = fz; n2 = fn;
    igbase += G3_;
  }
}

// ---------------- Fallback: naive (only if ws too small) ----------------
__global__ void __launch_bounds__(512) naive_kernel(const float* __restrict__ xs,
                                                    const float* __restrict__ Wih,
                                                    const float* __restrict__ Whh,
                                                    const float* __restrict__ bias,
                                                    const float* __restrict__ bn,
                                                    float* __restrict__ out) {
  const int b = blockIdx.x;
  const int j = threadIdx.x;
  __shared__ float h[H_];
  __shared__ float xr[D_];
  h[j] = 0.0f;
  __syncthreads();
  for (int t = 0; t < T_; ++t) {
    if (j < D_) xr[j] = xs[((size_t)b * T_ + t) * D_ + j];
    __syncthreads();
    float a[2];
#pragma unroll
    for (int g = 0; g < 2; ++g) {
      const int row = j + g * H_;
      float ssum = bias[row];
      const float* wi = Wih + (size_t)row * D_;
      for (int d = 0; d < D_; ++d) ssum = fmaf(wi[d], xr[d], ssum);
      const float* wh = Whh + (size_t)row * H_;
      for (int kk = 0; kk < H_; ++kk) ssum = fmaf(wh[kk], h[kk], ssum);
      a[g] = ssum;
    }
    const float r = sigmoidf_(a[0]);
    const float z = sigmoidf_(a[1]);
    float i_n = bias[j + 2 * H_];
    {
      const float* wi = Wih + (size_t)(j + 2 * H_) * D_;
      for (int d = 0; d < D_; ++d) i_n = fmaf(wi[d], xr[d], i_n);
    }
    float h_n = 0.0f;
    {
      const float* wh = Whh + (size_t)(j + 2 * H_) * H_;
      for (int kk = 0; kk < H_; ++kk) h_n = fmaf(wh[kk], h[kk], h_n);
    }
    const float nn = tanhf_(i_n + r * (h_n + bn[j]));
    const float hnew = nn + z * (h[j] - nn);
    __syncthreads();
    h[j] = hnew;
    out[((size_t)b * T_ + t) * H_ + j] = hnew;
  }
}

extern "C" void kernel_launch(void* const* d_in, const int* in_sizes, int n_in,
                              void* d_out, int out_size, void* d_ws, size_t ws_size,
                              hipStream_t stream) {
  const float* xs  = (const float*)d_in[0];
  const float* Wih = (const float*)d_in[1];
  const float* Whh = (const float*)d_in[2];
  const float* bia = (const float*)d_in[3];
  const float* bnp = (const float*)d_in[4];
  float* out = (float*)d_out;

  if (ws_size >= WS_NEED) {
    char* ws = (char*)d_ws;
    _Float16* igp = (_Float16*)(ws + OFF_IG);
    float* wtp = (float*)(ws + OFF_WT);
    uint32_t* mbp = (uint32_t*)(ws + OFF_MB);

    // zero tag mailboxes (stale-tag kill across graph replays)
    (void)hipMemsetAsync(mbp, 0, 2 * PAR_STRIDE * sizeof(uint32_t), stream);

    wt_kernel<<<dim3(384), dim3(256), 0, stream>>>(Wih, (float4*)wtp);
    ig_kernel<<<dim3((B_ * T_) / 16), dim3(256), 0, stream>>>(xs, wtp, bia, igp);
    rec_kernel<<<dim3(128), dim3(512), 0, stream>>>(igp, Whh, bnp, mbp, out);
  } else {
    naive_kernel<<<dim3(B_), dim3(H_), 0, stream>>>(xs, Wih, Whh, bia, bnp, out);
  }
}